// Round 13
// baseline (187.617 us; speedup 1.0000x reference)
//
#include <hip/hip_runtime.h>
#include <hip/hip_bf16.h>

#define S_LEN 2048
#define DM 768
#define NH 12
#define DH 64
#define BATCH 2
#define SC 0.1803368801111204f   // log2(e)/8  (folded into Wq, bq)
#define LOG2E 1.4426950408889634f

typedef __attribute__((ext_vector_type(8))) short bf16x8;
typedef __attribute__((ext_vector_type(4))) float f32x4;
typedef __attribute__((ext_vector_type(16))) float f32x16;
typedef __attribute__((ext_vector_type(8))) unsigned short u16x8;

__device__ __forceinline__ unsigned short f2bf(float f) {
  union { float f; unsigned u; } v; v.f = f;
  unsigned r = (v.u + 0x7fffu + ((v.u >> 16) & 1u)) >> 16;
  return (unsigned short)r;
}
__device__ __forceinline__ unsigned cvt2(float a, float b) {
  __hip_bfloat162 h = __float22bfloat162_rn(float2{a, b});
  return *reinterpret_cast<unsigned*>(&h);
}

// ---------------- W transpose + bf16 convert (+ fold log2e/8 into Wq) ----------------
__global__ __launch_bounds__(256) void wtrans(
    const float* __restrict__ Wq, const float* __restrict__ Wk, const float* __restrict__ Wv,
    unsigned short* __restrict__ Wt)
{
  const int z = blockIdx.z;
  const float* W = (z == 0) ? Wq : (z == 1) ? Wk : Wv;
  const float sc = (z == 0) ? SC : 1.0f;
  __shared__ float Lt[64][65];
  const int t = threadIdx.x;
  const int row0 = blockIdx.y * 64, col0 = blockIdx.x * 64;
  const int r = t >> 2, c0 = (t & 3) * 16;
  const float4* src = (const float4*)(W + (size_t)(row0 + r) * DM + col0 + c0);
  #pragma unroll
  for (int j = 0; j < 4; ++j) {
    const float4 v = src[j];
    Lt[r][c0 + 4 * j] = v.x; Lt[r][c0 + 4 * j + 1] = v.y;
    Lt[r][c0 + 4 * j + 2] = v.z; Lt[r][c0 + 4 * j + 3] = v.w;
  }
  __syncthreads();
  const int nn = t >> 2, kk0 = (t & 3) * 16;
  unsigned wo[8];
  #pragma unroll
  for (int j = 0; j < 8; ++j)
    wo[j] = cvt2(Lt[kk0 + 2 * j][nn] * sc, Lt[kk0 + 2 * j + 1][nn] * sc);
  unsigned short* dst = Wt + ((size_t)(z * DM + col0 + nn)) * DM + row0 + kk0;
  *(uint4*)dst = *(uint4*)&wo[0];
  *(uint4*)(dst + 8) = *(uint4*)&wo[4];
}

// ---------------- Fused Q/K/V projection GEMM: BM=128, BK=64, double-buffered LDS ----------------
// One barrier per k-iter (13 total vs 24); next tile's global loads issued
// before the current tile's MFMAs so load latency hides under compute.
#define BM 128
#define BN 128
#define BK 64
#define LDPAD 72
#define NKT (DM / BK)   // 12

__global__ __launch_bounds__(256) void qkv_gemm(
    const float* __restrict__ X,
    const unsigned short* __restrict__ Wt,
    const float* __restrict__ bq, const float* __restrict__ bk, const float* __restrict__ bv,
    unsigned short* __restrict__ Qo, unsigned short* __restrict__ Kf,
    unsigned short* __restrict__ Vf)
{
  const int z = blockIdx.z;
  const float* bias = (z == 0) ? bq : (z == 1) ? bk : bv;
  const float bsc = (z == 0) ? SC : 1.0f;

  __shared__ __align__(16) unsigned short Al[2][BM][LDPAD];
  __shared__ __align__(16) unsigned short Bl[2][BN][LDPAD];

  const int t = threadIdx.x;
  const int wv = t >> 6, lane = t & 63;
  const int g = lane >> 4, c = lane & 15;
  const int wm = (wv >> 1) * 64, wn = (wv & 1) * 64;
  const int m0 = blockIdx.y * BM, n0 = blockIdx.x * BN;

  f32x4 acc[4][4];
  #pragma unroll
  for (int i = 0; i < 4; ++i)
    #pragma unroll
    for (int j = 0; j < 4; ++j) {
      float bb = bias[n0 + wn + j * 16 + c] * bsc;
      f32x4 a4 = {bb, bb, bb, bb};
      acc[i][j] = a4;
    }

  const int a_m = t >> 1, a_k = (t & 1) * 32;

  // staged registers: X converted to bf16 at load (4x uint4), W raw (4x u16x8)
  uint4 xa[4];
  u16x8 wb[4];
  auto stage_regs = [&](int kt) {
    const int k0 = kt * BK;
    #pragma unroll
    for (int half = 0; half < 2; ++half) {
      const float4* src = (const float4*)(X + (size_t)(m0 + a_m) * DM + k0 + a_k + 16 * half);
      const float4 x0 = src[0], x1 = src[1], x2 = src[2], x3 = src[3];
      xa[2 * half]     = uint4{cvt2(x0.x, x0.y), cvt2(x0.z, x0.w), cvt2(x1.x, x1.y), cvt2(x1.z, x1.w)};
      xa[2 * half + 1] = uint4{cvt2(x2.x, x2.y), cvt2(x2.z, x2.w), cvt2(x3.x, x3.y), cvt2(x3.z, x3.w)};
    }
    const unsigned short* srcB = Wt + ((size_t)(z * DM + n0 + a_m)) * DM + k0 + a_k;
    #pragma unroll
    for (int j = 0; j < 4; ++j) wb[j] = *(const u16x8*)(srcB + 8 * j);
  };
  auto write_buf = [&](int buf) {
    *(uint4*)&Al[buf][a_m][a_k]      = xa[0];
    *(uint4*)&Al[buf][a_m][a_k + 8]  = xa[1];
    *(uint4*)&Al[buf][a_m][a_k + 16] = xa[2];
    *(uint4*)&Al[buf][a_m][a_k + 24] = xa[3];
    #pragma unroll
    for (int j = 0; j < 4; ++j) *(u16x8*)&Bl[buf][a_m][a_k + 8 * j] = wb[j];
  };

  stage_regs(0);
  write_buf(0);
  __syncthreads();

  for (int kt = 0; kt < NKT; ++kt) {
    const int cur = kt & 1;
    if (kt + 1 < NKT) stage_regs(kt + 1);   // issue next-tile loads before MFMAs
    #pragma unroll
    for (int kk = 0; kk < 2; ++kk) {
      bf16x8 af[4], bfr[4];
      #pragma unroll
      for (int i = 0; i < 4; ++i) af[i]  = *(const bf16x8*)&Al[cur][wm + i * 16 + c][kk * 32 + 8 * g];
      #pragma unroll
      for (int j = 0; j < 4; ++j) bfr[j] = *(const bf16x8*)&Bl[cur][wn + j * 16 + c][kk * 32 + 8 * g];
      #pragma unroll
      for (int i = 0; i < 4; ++i)
        #pragma unroll
        for (int j = 0; j < 4; ++j)
          acc[i][j] = __builtin_amdgcn_mfma_f32_16x16x32_bf16(af[i], bfr[j], acc[i][j], 0, 0, 0);
    }
    if (kt + 1 < NKT) write_buf(cur ^ 1);
    __syncthreads();
  }

  if (z == 0) {
    #pragma unroll
    for (int i = 0; i < 4; ++i)
      #pragma unroll
      for (int j = 0; j < 4; ++j)
        #pragma unroll
        for (int r = 0; r < 4; ++r) {
          const int m = m0 + wm + i * 16 + 4 * g + r;
          const int n = n0 + wn + j * 16 + c;
          Qo[(size_t)m * DM + n] = f2bf(acc[i][j][r]);
        }
  } else if (z == 1) {
    #pragma unroll
    for (int i = 0; i < 4; ++i)
      #pragma unroll
      for (int j = 0; j < 4; ++j) {
        const int n = n0 + wn + j * 16 + c;
        const int h = n >> 6, d = n & 63, ch = d >> 3, e = d & 7;
        #pragma unroll
        for (int r = 0; r < 4; ++r) {
          const int m = m0 + wm + i * 16 + 4 * g + r;
          const int b = m >> 11, s = m & 2047;
          const int st = s >> 5, r32 = s & 31;
          const size_t w = (((size_t)(b * NH + h) * 64 + st) * 8 + ch) * 32 + r32;
          Kf[w * 8 + e] = f2bf(acc[i][j][r]);
        }
      }
  } else {
    #pragma unroll
    for (int i = 0; i < 4; ++i)
      #pragma unroll
      for (int j = 0; j < 4; ++j) {
        const int n = n0 + wn + j * 16 + c;
        const int h = n >> 6, d = n & 63;
        const int mb = m0 + wm + i * 16 + 4 * g;
        const int b = mb >> 11, s = mb & 2047;
        const int kk = s >> 3, j0 = s & 7;
        unsigned short* dst = &Vf[(((size_t)(b * NH + h) * 256 + kk) * 64 + d) * 8 + j0];
        uint2 pk = {cvt2(acc[i][j][0], acc[i][j][1]), cvt2(acc[i][j][2], acc[i][j][3])};
        *(uint2*)dst = pk;
      }
  }
}

// ---------------- Fused attention: r11 structure + s_setprio around MFMA ----------------
__global__ __launch_bounds__(256, 3) void attn_fused(
    const unsigned short* __restrict__ Qb,
    const bf16x8* __restrict__ Kf,
    const bf16x8* __restrict__ Vf,
    const float* __restrict__ mask,   // [B][S]
    float* __restrict__ ctx,          // [B][S][768]
    float* __restrict__ Pout)         // [B][H][S][S]
{
  const int bid = blockIdx.x;
  const int wg = (bid & 7) * 192 + (bid >> 3);   // bijective XCD swizzle (1536 = 8*192)
  const int qt = wg & 63;
  const int bh = wg >> 6;
  const int b = bh / NH, h = bh % NH;

  const int t = threadIdx.x, wv = t >> 6, lane = t & 63;
  const int q = lane & 31, hi = lane >> 5;
  const int q0 = qt * 32;

  __shared__ __align__(16) float Pf[4][2][32][36];   // 2-deep: write cur, store prev
  __shared__ __align__(16) float Osum[32][68];
  __shared__ float mlb[4][32];

  bf16x8 bqf[4];
  {
    const unsigned short* qp = Qb + (size_t)(b * S_LEN + q0 + q) * DM + h * DH + 8 * hi;
    #pragma unroll
    for (int m = 0; m < 4; ++m) bqf[m] = *(const bf16x8*)(qp + 16 * m);
  }

  const bf16x8* kfb = Kf + ((size_t)bh * 64 + wv * 16) * 256;
  const bf16x8* vfb = Vf + ((size_t)bh * 256 + wv * 64) * 64;
  const float* mrow = mask + (size_t)b * S_LEN + wv * 512;

  float ll = 0.f;

  // ---- pass 1: per-lane row-sum of exp2(s), K double-buffered ----
  bf16x8 kc[4];
  #pragma unroll
  for (int m = 0; m < 4; ++m) kc[m] = kfb[(2 * m + hi) * 32 + q];

  for (int st = 0; st < 16; ++st) {
    bf16x8 kn[4];
    const int stn = (st + 1) & 15;
    #pragma unroll
    for (int m = 0; m < 4; ++m) kn[m] = kfb[stn * 256 + (2 * m + hi) * 32 + q];

    f32x16 s;
    #pragma unroll
    for (int rg = 0; rg < 4; ++rg) {
      const f32x4 mk = *(const f32x4*)&mrow[st * 32 + 8 * rg + 4 * hi];
      #pragma unroll
      for (int ri = 0; ri < 4; ++ri) s[4 * rg + ri] = mk[ri] * LOG2E;
    }
    __builtin_amdgcn_s_setprio(1);
    #pragma unroll
    for (int m = 0; m < 4; ++m)
      s = __builtin_amdgcn_mfma_f32_32x32x16_bf16(kc[m], bqf[m], s, 0, 0, 0);
    __builtin_amdgcn_s_setprio(0);

    float e[16];
    #pragma unroll
    for (int r = 0; r < 16; ++r) e[r] = __builtin_amdgcn_exp2f(s[r]);
    const float t0 = (e[0] + e[1]) + (e[2] + e[3]);
    const float t1 = (e[4] + e[5]) + (e[6] + e[7]);
    const float t2 = (e[8] + e[9]) + (e[10] + e[11]);
    const float t3 = (e[12] + e[13]) + (e[14] + e[15]);
    ll += (t0 + t1) + (t2 + t3);
    #pragma unroll
    for (int m = 0; m < 4; ++m) kc[m] = kn[m];
  }
  ll += __shfl_xor(ll, 32);
  if (hi == 0) mlb[wv][q] = ll;
  __syncthreads();

  const float lsum = (mlb[0][q] + mlb[1][q]) + (mlb[2][q] + mlb[3][q]);
  const float mfin = __builtin_amdgcn_logf(lsum);   // v_log_f32 = log2

  // ---- pass 2: recompute, 2-deep P staging, coalesced store, PV ----
  f32x16 o0, o1;
  #pragma unroll
  for (int r = 0; r < 16; ++r) { o0[r] = 0.f; o1[r] = 0.f; }

  float* pbase = Pout + (size_t)bh * S_LEN * S_LEN + (size_t)q0 * S_LEN + wv * 512;
  const int sr = lane >> 3, scl = lane & 7;

  // kc already holds st=0 (pass 1's wraparound prefetch survived the barrier)
  for (int st = 0; st < 16; ++st) {
    const int cur = st & 1;
    bf16x8 kn[4];
    const int stn = (st + 1) & 15;
    #pragma unroll
    for (int m = 0; m < 4; ++m) kn[m] = kfb[stn * 256 + (2 * m + hi) * 32 + q];

    // V loads early: latency hides under the QK MFMA chain + exp2
    const bf16x8 vb00 = vfb[(st * 4 + hi) * 64 + q];
    const bf16x8 vb01 = vfb[(st * 4 + hi) * 64 + 32 + q];
    const bf16x8 vb10 = vfb[(st * 4 + 2 + hi) * 64 + q];
    const bf16x8 vb11 = vfb[(st * 4 + 2 + hi) * 64 + 32 + q];

    f32x16 s;
    #pragma unroll
    for (int rg = 0; rg < 4; ++rg) {
      const f32x4 mk = *(const f32x4*)&mrow[st * 32 + 8 * rg + 4 * hi];
      #pragma unroll
      for (int ri = 0; ri < 4; ++ri) s[4 * rg + ri] = mk[ri] * LOG2E;
    }
    __builtin_amdgcn_s_setprio(1);
    #pragma unroll
    for (int m = 0; m < 4; ++m)
      s = __builtin_amdgcn_mfma_f32_32x32x16_bf16(kc[m], bqf[m], s, 0, 0, 0);
    __builtin_amdgcn_s_setprio(0);

    #pragma unroll
    for (int r = 0; r < 16; ++r) s[r] = __builtin_amdgcn_exp2f(s[r] - mfin);

    // stage fp32 P subtile into the CURRENT buffer
    #pragma unroll
    for (int rg = 0; rg < 4; ++rg) {
      f32x4 pv = {s[4 * rg], s[4 * rg + 1], s[4 * rg + 2], s[4 * rg + 3]};
      *(f32x4*)&Pf[wv][cur][q][8 * rg + 4 * hi] = pv;
    }

    // PV A-fragment in-register: cvt_pk pairs + permlane32_swap across hi halves
    unsigned c0 = cvt2(s[0], s[1]),   c1 = cvt2(s[2], s[3]);
    unsigned c2 = cvt2(s[4], s[5]),   c3 = cvt2(s[6], s[7]);
    unsigned c4 = cvt2(s[8], s[9]),   c5 = cvt2(s[10], s[11]);
    unsigned c6 = cvt2(s[12], s[13]), c7 = cvt2(s[14], s[15]);
    auto r02 = __builtin_amdgcn_permlane32_swap(c0, c2, false, false);
    auto r13 = __builtin_amdgcn_permlane32_swap(c1, c3, false, false);
    auto r46 = __builtin_amdgcn_permlane32_swap(c4, c6, false, false);
    auto r57 = __builtin_amdgcn_permlane32_swap(c5, c7, false, false);
    uint4 u0 = {r02[0], r13[0], r02[1], r13[1]};
    uint4 u1 = {r46[0], r57[0], r46[1], r57[1]};
    const bf16x8 pa0 = *reinterpret_cast<bf16x8*>(&u0);
    const bf16x8 pa1 = *reinterpret_cast<bf16x8*>(&u1);

    __builtin_amdgcn_s_setprio(1);
    o0 = __builtin_amdgcn_mfma_f32_32x32x16_bf16(pa0, vb00, o0, 0, 0, 0);
    o0 = __builtin_amdgcn_mfma_f32_32x32x16_bf16(pa1, vb10, o0, 0, 0, 0);
    o1 = __builtin_amdgcn_mfma_f32_32x32x16_bf16(pa0, vb01, o1, 0, 0, 0);
    o1 = __builtin_amdgcn_mfma_f32_32x32x16_bf16(pa1, vb11, o1, 0, 0, 0);
    __builtin_amdgcn_s_setprio(0);

    // store the PREVIOUS subtile (its LDS writes had a full iteration to land)
    if (st > 0) {
      float* pst = pbase + (st - 1) * 32;
      #pragma unroll
      for (int i = 0; i < 4; ++i) {
        const f32x4 row = *(const f32x4*)&Pf[wv][cur ^ 1][sr + 8 * i][scl * 4];
        *(f32x4*)(pst + (size_t)(sr + 8 * i) * S_LEN + scl * 4) = row;
      }
    }
    #pragma unroll
    for (int m = 0; m < 4; ++m) kc[m] = kn[m];
  }
  {  // drain the last subtile (st=15 wrote buffer 1)
    float* pst = pbase + 15 * 32;
    #pragma unroll
    for (int i = 0; i < 4; ++i) {
      const f32x4 row = *(const f32x4*)&Pf[wv][1][sr + 8 * i][scl * 4];
      *(f32x4*)(pst + (size_t)(sr + 8 * i) * S_LEN + scl * 4) = row;
    }
  }

  // ---- O merge across the 4 k-split waves, then coalesced store ----
  #pragma unroll
  for (int w = 0; w < 4; ++w) {
    if (wv == w) {
      #pragma unroll
      for (int rg = 0; rg < 4; ++rg)
        #pragma unroll
        for (int ri = 0; ri < 4; ++ri) {
          const int qr = ri + 8 * rg + 4 * hi;
          if (w == 0) {
            Osum[qr][q]      = o0[4 * rg + ri];
            Osum[qr][32 + q] = o1[4 * rg + ri];
          } else {
            Osum[qr][q]      += o0[4 * rg + ri];
            Osum[qr][32 + q] += o1[4 * rg + ri];
          }
        }
    }
    __syncthreads();
  }

  const int row = t >> 3, d0 = (t & 7) * 8;
  const f32x4 r0 = *(const f32x4*)&Osum[row][d0];
  const f32x4 r1 = *(const f32x4*)&Osum[row][d0 + 4];
  float* crow = ctx + (size_t)(b * S_LEN + q0 + row) * DM + h * DH + d0;
  *(f32x4*)crow = r0;
  *(f32x4*)(crow + 4) = r1;
}

extern "C" void kernel_launch(void* const* d_in, const int* in_sizes, int n_in,
                              void* d_out, int out_size, void* d_ws, size_t ws_size,
                              hipStream_t stream) {
  const float* hs   = (const float*)d_in[0];
  const float* mask = (const float*)d_in[1];
  const float* Wq = (const float*)d_in[2];
  const float* bq = (const float*)d_in[3];
  const float* Wk = (const float*)d_in[4];
  const float* bk = (const float*)d_in[5];
  const float* Wv = (const float*)d_in[6];
  const float* bv = (const float*)d_in[7];

  const size_t MT = (size_t)BATCH * S_LEN * DM;
  unsigned short* Qb = (unsigned short*)d_ws;
  unsigned short* Kf = Qb + MT;
  unsigned short* Vf = Kf + MT;
  unsigned short* Wt = Vf + MT;   // 3*768*768 bf16 = 3.5 MB

  float* ctx  = (float*)d_out;
  float* Pout = ctx + MT;

  wtrans<<<dim3(12, 12, 3), 256, 0, stream>>>(Wq, Wk, Wv, Wt);
  qkv_gemm<<<dim3(DM / BN, (BATCH * S_LEN) / BM, 3), 256, 0, stream>>>(
      hs, Wt, bq, bk, bv, Qb, Kf, Vf);
  attn_fused<<<dim3((S_LEN / 32) * NH * BATCH), 256, 0, stream>>>(
      Qb, (const bf16x8*)Kf, (const bf16x8*)Vf, mask, ctx, Pout);
}

// Round 14
// 171.073 us; speedup vs baseline: 1.0967x; 1.0967x over previous
//
#include <hip/hip_runtime.h>
#include <hip/hip_bf16.h>

#define S_LEN 2048
#define DM 768
#define NH 12
#define DH 64
#define BATCH 2
#define SC 0.1803368801111204f   // log2(e)/8  (folded into Wq, bq)
#define LOG2E 1.4426950408889634f

typedef __attribute__((ext_vector_type(8))) short bf16x8;
typedef __attribute__((ext_vector_type(4))) float f32x4;
typedef __attribute__((ext_vector_type(16))) float f32x16;
typedef __attribute__((ext_vector_type(8))) unsigned short u16x8;

__device__ __forceinline__ unsigned short f2bf(float f) {
  union { float f; unsigned u; } v; v.f = f;
  unsigned r = (v.u + 0x7fffu + ((v.u >> 16) & 1u)) >> 16;
  return (unsigned short)r;
}
__device__ __forceinline__ unsigned cvt2(float a, float b) {
  __hip_bfloat162 h = __float22bfloat162_rn(float2{a, b});
  return *reinterpret_cast<unsigned*>(&h);
}

// ---------------- W transpose + bf16 convert (+ fold log2e/8 into Wq) ----------------
__global__ __launch_bounds__(256) void wtrans(
    const float* __restrict__ Wq, const float* __restrict__ Wk, const float* __restrict__ Wv,
    unsigned short* __restrict__ Wt)
{
  const int z = blockIdx.z;
  const float* W = (z == 0) ? Wq : (z == 1) ? Wk : Wv;
  const float sc = (z == 0) ? SC : 1.0f;
  __shared__ float Lt[64][65];
  const int t = threadIdx.x;
  const int row0 = blockIdx.y * 64, col0 = blockIdx.x * 64;
  const int r = t >> 2, c0 = (t & 3) * 16;
  const float4* src = (const float4*)(W + (size_t)(row0 + r) * DM + col0 + c0);
  #pragma unroll
  for (int j = 0; j < 4; ++j) {
    const float4 v = src[j];
    Lt[r][c0 + 4 * j] = v.x; Lt[r][c0 + 4 * j + 1] = v.y;
    Lt[r][c0 + 4 * j + 2] = v.z; Lt[r][c0 + 4 * j + 3] = v.w;
  }
  __syncthreads();
  const int nn = t >> 2, kk0 = (t & 3) * 16;
  unsigned wo[8];
  #pragma unroll
  for (int j = 0; j < 8; ++j)
    wo[j] = cvt2(Lt[kk0 + 2 * j][nn] * sc, Lt[kk0 + 2 * j + 1][nn] * sc);
  unsigned short* dst = Wt + ((size_t)(z * DM + col0 + nn)) * DM + row0 + kk0;
  *(uint4*)dst = *(uint4*)&wo[0];
  *(uint4*)(dst + 8) = *(uint4*)&wo[4];
}

// ---------------- Fused Q/K/V projection GEMM (r11 config: BM=128, BK=64, single-buffer) ----------------
#define BM 128
#define BN 128
#define BK 64
#define LDPAD 72

__global__ __launch_bounds__(256) void qkv_gemm(
    const float* __restrict__ X,
    const unsigned short* __restrict__ Wt,
    const float* __restrict__ bq, const float* __restrict__ bk, const float* __restrict__ bv,
    unsigned short* __restrict__ Qo, unsigned short* __restrict__ Kf,
    unsigned short* __restrict__ Vf)
{
  const int z = blockIdx.z;
  const float* bias = (z == 0) ? bq : (z == 1) ? bk : bv;
  const float bsc = (z == 0) ? SC : 1.0f;

  __shared__ __align__(16) unsigned short Al[BM][LDPAD];
  __shared__ __align__(16) unsigned short Bl[BN][LDPAD];

  const int t = threadIdx.x;
  const int wv = t >> 6, lane = t & 63;
  const int g = lane >> 4, c = lane & 15;
  const int wm = (wv >> 1) * 64, wn = (wv & 1) * 64;
  const int m0 = blockIdx.y * BM, n0 = blockIdx.x * BN;

  f32x4 acc[4][4];
  #pragma unroll
  for (int i = 0; i < 4; ++i)
    #pragma unroll
    for (int j = 0; j < 4; ++j) {
      float bb = bias[n0 + wn + j * 16 + c] * bsc;
      f32x4 a4 = {bb, bb, bb, bb};
      acc[i][j] = a4;
    }

  const int a_m = t >> 1, a_k = (t & 1) * 32;

  for (int kt = 0; kt < DM / BK; ++kt) {
    const int k0 = kt * BK;
    __syncthreads();
    #pragma unroll
    for (int half = 0; half < 2; ++half) {
      const float4* src = (const float4*)(X + (size_t)(m0 + a_m) * DM + k0 + a_k + 16 * half);
      const float4 x0 = src[0], x1 = src[1], x2 = src[2], x3 = src[3];
      uint4 v0 = {cvt2(x0.x, x0.y), cvt2(x0.z, x0.w), cvt2(x1.x, x1.y), cvt2(x1.z, x1.w)};
      uint4 v1 = {cvt2(x2.x, x2.y), cvt2(x2.z, x2.w), cvt2(x3.x, x3.y), cvt2(x3.z, x3.w)};
      *(uint4*)&Al[a_m][a_k + 16 * half] = v0;
      *(uint4*)&Al[a_m][a_k + 16 * half + 8] = v1;
    }
    {
      const unsigned short* srcB = Wt + ((size_t)(z * DM + n0 + a_m)) * DM + k0 + a_k;
      const u16x8 w0 = *(const u16x8*)srcB;
      const u16x8 w1 = *(const u16x8*)(srcB + 8);
      const u16x8 w2 = *(const u16x8*)(srcB + 16);
      const u16x8 w3 = *(const u16x8*)(srcB + 24);
      *(u16x8*)&Bl[a_m][a_k] = w0;
      *(u16x8*)&Bl[a_m][a_k + 8] = w1;
      *(u16x8*)&Bl[a_m][a_k + 16] = w2;
      *(u16x8*)&Bl[a_m][a_k + 24] = w3;
    }
    __syncthreads();
    #pragma unroll
    for (int kk = 0; kk < 2; ++kk) {
      bf16x8 af[4], bfr[4];
      #pragma unroll
      for (int i = 0; i < 4; ++i) af[i]  = *(const bf16x8*)&Al[wm + i * 16 + c][kk * 32 + 8 * g];
      #pragma unroll
      for (int j = 0; j < 4; ++j) bfr[j] = *(const bf16x8*)&Bl[wn + j * 16 + c][kk * 32 + 8 * g];
      #pragma unroll
      for (int i = 0; i < 4; ++i)
        #pragma unroll
        for (int j = 0; j < 4; ++j)
          acc[i][j] = __builtin_amdgcn_mfma_f32_16x16x32_bf16(af[i], bfr[j], acc[i][j], 0, 0, 0);
    }
  }

  if (z == 0) {
    #pragma unroll
    for (int i = 0; i < 4; ++i)
      #pragma unroll
      for (int j = 0; j < 4; ++j)
        #pragma unroll
        for (int r = 0; r < 4; ++r) {
          const int m = m0 + wm + i * 16 + 4 * g + r;
          const int n = n0 + wn + j * 16 + c;
          Qo[(size_t)m * DM + n] = f2bf(acc[i][j][r]);
        }
  } else if (z == 1) {
    #pragma unroll
    for (int i = 0; i < 4; ++i)
      #pragma unroll
      for (int j = 0; j < 4; ++j) {
        const int n = n0 + wn + j * 16 + c;
        const int h = n >> 6, d = n & 63, ch = d >> 3, e = d & 7;
        #pragma unroll
        for (int r = 0; r < 4; ++r) {
          const int m = m0 + wm + i * 16 + 4 * g + r;
          const int b = m >> 11, s = m & 2047;
          const int st = s >> 5, r32 = s & 31;
          const size_t w = (((size_t)(b * NH + h) * 64 + st) * 8 + ch) * 32 + r32;
          Kf[w * 8 + e] = f2bf(acc[i][j][r]);
        }
      }
  } else {
    #pragma unroll
    for (int i = 0; i < 4; ++i)
      #pragma unroll
      for (int j = 0; j < 4; ++j) {
        const int n = n0 + wn + j * 16 + c;
        const int h = n >> 6, d = n & 63;
        const int mb = m0 + wm + i * 16 + 4 * g;
        const int b = mb >> 11, s = mb & 2047;
        const int kk = s >> 3, j0 = s & 7;
        unsigned short* dst = &Vf[(((size_t)(b * NH + h) * 256 + kk) * 64 + d) * 8 + j0];
        uint2 pk = {cvt2(acc[i][j][0], acc[i][j][1]), cvt2(acc[i][j][2], acc[i][j][3])};
        *(uint2*)dst = pk;
      }
  }
}

// ---------------- Fused attention: r11 structure + parallel O-merge ----------------
// Block = 32 q-rows; 4 waves own disjoint 512-k ranges. Max-free softmax.
// Pass 2: K double-buffered, V hoisted, P staged in a 2-deep LDS buffer stored
// coalesced one iteration later. O-merge: Pf reused as scratch (dead after the
// P drain) -> all-wave parallel write + single reduction, 2 barriers total.
__global__ __launch_bounds__(256, 3) void attn_fused(
    const unsigned short* __restrict__ Qb,
    const bf16x8* __restrict__ Kf,
    const bf16x8* __restrict__ Vf,
    const float* __restrict__ mask,   // [B][S]
    float* __restrict__ ctx,          // [B][S][768]
    float* __restrict__ Pout)         // [B][H][S][S]
{
  const int bid = blockIdx.x;
  const int wg = (bid & 7) * 192 + (bid >> 3);   // bijective XCD swizzle (1536 = 8*192)
  const int qt = wg & 63;
  const int bh = wg >> 6;
  const int b = bh / NH, h = bh % NH;

  const int t = threadIdx.x, wv = t >> 6, lane = t & 63;
  const int q = lane & 31, hi = lane >> 5;
  const int q0 = qt * 32;

  __shared__ __align__(16) float Pf[4][2][32][36];   // 36.9 KB; reused as O-merge scratch
  __shared__ float mlb[4][32];

  bf16x8 bqf[4];
  {
    const unsigned short* qp = Qb + (size_t)(b * S_LEN + q0 + q) * DM + h * DH + 8 * hi;
    #pragma unroll
    for (int m = 0; m < 4; ++m) bqf[m] = *(const bf16x8*)(qp + 16 * m);
  }

  const bf16x8* kfb = Kf + ((size_t)bh * 64 + wv * 16) * 256;
  const bf16x8* vfb = Vf + ((size_t)bh * 256 + wv * 64) * 64;
  const float* mrow = mask + (size_t)b * S_LEN + wv * 512;

  float ll = 0.f;

  // ---- pass 1: per-lane row-sum of exp2(s), K double-buffered ----
  bf16x8 kc[4];
  #pragma unroll
  for (int m = 0; m < 4; ++m) kc[m] = kfb[(2 * m + hi) * 32 + q];

  for (int st = 0; st < 16; ++st) {
    bf16x8 kn[4];
    const int stn = (st + 1) & 15;
    #pragma unroll
    for (int m = 0; m < 4; ++m) kn[m] = kfb[stn * 256 + (2 * m + hi) * 32 + q];

    f32x16 s;
    #pragma unroll
    for (int rg = 0; rg < 4; ++rg) {
      const f32x4 mk = *(const f32x4*)&mrow[st * 32 + 8 * rg + 4 * hi];
      #pragma unroll
      for (int ri = 0; ri < 4; ++ri) s[4 * rg + ri] = mk[ri] * LOG2E;
    }
    #pragma unroll
    for (int m = 0; m < 4; ++m)
      s = __builtin_amdgcn_mfma_f32_32x32x16_bf16(kc[m], bqf[m], s, 0, 0, 0);

    float e[16];
    #pragma unroll
    for (int r = 0; r < 16; ++r) e[r] = __builtin_amdgcn_exp2f(s[r]);
    const float t0 = (e[0] + e[1]) + (e[2] + e[3]);
    const float t1 = (e[4] + e[5]) + (e[6] + e[7]);
    const float t2 = (e[8] + e[9]) + (e[10] + e[11]);
    const float t3 = (e[12] + e[13]) + (e[14] + e[15]);
    ll += (t0 + t1) + (t2 + t3);
    #pragma unroll
    for (int m = 0; m < 4; ++m) kc[m] = kn[m];
  }
  ll += __shfl_xor(ll, 32);
  if (hi == 0) mlb[wv][q] = ll;
  __syncthreads();

  const float lsum = (mlb[0][q] + mlb[1][q]) + (mlb[2][q] + mlb[3][q]);
  const float mfin = __builtin_amdgcn_logf(lsum);   // v_log_f32 = log2

  // ---- pass 2: recompute, 2-deep P staging, coalesced store, PV ----
  f32x16 o0, o1;
  #pragma unroll
  for (int r = 0; r < 16; ++r) { o0[r] = 0.f; o1[r] = 0.f; }

  float* pbase = Pout + (size_t)bh * S_LEN * S_LEN + (size_t)q0 * S_LEN + wv * 512;
  const int sr = lane >> 3, scl = lane & 7;

  // kc already holds st=0 (pass 1's wraparound prefetch survived the barrier)
  for (int st = 0; st < 16; ++st) {
    const int cur = st & 1;
    bf16x8 kn[4];
    const int stn = (st + 1) & 15;
    #pragma unroll
    for (int m = 0; m < 4; ++m) kn[m] = kfb[stn * 256 + (2 * m + hi) * 32 + q];

    // V loads early: latency hides under the QK MFMA chain + exp2
    const bf16x8 vb00 = vfb[(st * 4 + hi) * 64 + q];
    const bf16x8 vb01 = vfb[(st * 4 + hi) * 64 + 32 + q];
    const bf16x8 vb10 = vfb[(st * 4 + 2 + hi) * 64 + q];
    const bf16x8 vb11 = vfb[(st * 4 + 2 + hi) * 64 + 32 + q];

    f32x16 s;
    #pragma unroll
    for (int rg = 0; rg < 4; ++rg) {
      const f32x4 mk = *(const f32x4*)&mrow[st * 32 + 8 * rg + 4 * hi];
      #pragma unroll
      for (int ri = 0; ri < 4; ++ri) s[4 * rg + ri] = mk[ri] * LOG2E;
    }
    #pragma unroll
    for (int m = 0; m < 4; ++m)
      s = __builtin_amdgcn_mfma_f32_32x32x16_bf16(kc[m], bqf[m], s, 0, 0, 0);

    #pragma unroll
    for (int r = 0; r < 16; ++r) s[r] = __builtin_amdgcn_exp2f(s[r] - mfin);

    // stage fp32 P subtile into the CURRENT buffer
    #pragma unroll
    for (int rg = 0; rg < 4; ++rg) {
      f32x4 pv = {s[4 * rg], s[4 * rg + 1], s[4 * rg + 2], s[4 * rg + 3]};
      *(f32x4*)&Pf[wv][cur][q][8 * rg + 4 * hi] = pv;
    }

    // PV A-fragment in-register: cvt_pk pairs + permlane32_swap across hi halves
    unsigned c0 = cvt2(s[0], s[1]),   c1 = cvt2(s[2], s[3]);
    unsigned c2 = cvt2(s[4], s[5]),   c3 = cvt2(s[6], s[7]);
    unsigned c4 = cvt2(s[8], s[9]),   c5 = cvt2(s[10], s[11]);
    unsigned c6 = cvt2(s[12], s[13]), c7 = cvt2(s[14], s[15]);
    auto r02 = __builtin_amdgcn_permlane32_swap(c0, c2, false, false);
    auto r13 = __builtin_amdgcn_permlane32_swap(c1, c3, false, false);
    auto r46 = __builtin_amdgcn_permlane32_swap(c4, c6, false, false);
    auto r57 = __builtin_amdgcn_permlane32_swap(c5, c7, false, false);
    uint4 u0 = {r02[0], r13[0], r02[1], r13[1]};
    uint4 u1 = {r46[0], r57[0], r46[1], r57[1]};
    const bf16x8 pa0 = *reinterpret_cast<bf16x8*>(&u0);
    const bf16x8 pa1 = *reinterpret_cast<bf16x8*>(&u1);

    o0 = __builtin_amdgcn_mfma_f32_32x32x16_bf16(pa0, vb00, o0, 0, 0, 0);
    o0 = __builtin_amdgcn_mfma_f32_32x32x16_bf16(pa1, vb10, o0, 0, 0, 0);
    o1 = __builtin_amdgcn_mfma_f32_32x32x16_bf16(pa0, vb01, o1, 0, 0, 0);
    o1 = __builtin_amdgcn_mfma_f32_32x32x16_bf16(pa1, vb11, o1, 0, 0, 0);

    // store the PREVIOUS subtile (its LDS writes had a full iteration to land)
    if (st > 0) {
      float* pst = pbase + (st - 1) * 32;
      #pragma unroll
      for (int i = 0; i < 4; ++i) {
        const f32x4 row = *(const f32x4*)&Pf[wv][cur ^ 1][sr + 8 * i][scl * 4];
        *(f32x4*)(pst + (size_t)(sr + 8 * i) * S_LEN + scl * 4) = row;
      }
    }
    #pragma unroll
    for (int m = 0; m < 4; ++m) kc[m] = kn[m];
  }
  {  // drain the last subtile (st=15 wrote buffer 1)
    float* pst = pbase + 15 * 32;
    #pragma unroll
    for (int i = 0; i < 4; ++i) {
      const f32x4 row = *(const f32x4*)&Pf[wv][1][sr + 8 * i][scl * 4];
      *(f32x4*)(pst + (size_t)(sr + 8 * i) * S_LEN + scl * 4) = row;
    }
  }

  // ---- O merge: Pf reused as scratch, all-wave parallel, 2 barriers ----
  __syncthreads();   // every wave is past its last Pf read
  float (*Osc)[32][68] = (float(*)[32][68])(&Pf[0][0][0][0]);  // 34.8 KB <= 36.9 KB
  #pragma unroll
  for (int rg = 0; rg < 4; ++rg)
    #pragma unroll
    for (int ri = 0; ri < 4; ++ri) {
      const int qr = ri + 8 * rg + 4 * hi;
      Osc[wv][qr][q]      = o0[4 * rg + ri];
      Osc[wv][qr][32 + q] = o1[4 * rg + ri];
    }
  __syncthreads();

  const int row = t >> 3, d0 = (t & 7) * 8;
  f32x4 r0 = *(const f32x4*)&Osc[0][row][d0];
  f32x4 r1 = *(const f32x4*)&Osc[0][row][d0 + 4];
  #pragma unroll
  for (int w = 1; w < 4; ++w) {
    r0 += *(const f32x4*)&Osc[w][row][d0];
    r1 += *(const f32x4*)&Osc[w][row][d0 + 4];
  }
  float* crow = ctx + (size_t)(b * S_LEN + q0 + row) * DM + h * DH + d0;
  *(f32x4*)crow = r0;
  *(f32x4*)(crow + 4) = r1;
}

extern "C" void kernel_launch(void* const* d_in, const int* in_sizes, int n_in,
                              void* d_out, int out_size, void* d_ws, size_t ws_size,
                              hipStream_t stream) {
  const float* hs   = (const float*)d_in[0];
  const float* mask = (const float*)d_in[1];
  const float* Wq = (const float*)d_in[2];
  const float* bq = (const float*)d_in[3];
  const float* Wk = (const float*)d_in[4];
  const float* bk = (const float*)d_in[5];
  const float* Wv = (const float*)d_in[6];
  const float* bv = (const float*)d_in[7];

  const size_t MT = (size_t)BATCH * S_LEN * DM;
  unsigned short* Qb = (unsigned short*)d_ws;
  unsigned short* Kf = Qb + MT;
  unsigned short* Vf = Kf + MT;
  unsigned short* Wt = Vf + MT;   // 3*768*768 bf16 = 3.5 MB

  float* ctx  = (float*)d_out;
  float* Pout = ctx + MT;

  wtrans<<<dim3(12, 12, 3), 256, 0, stream>>>(Wq, Wk, Wv, Wt);
  qkv_gemm<<<dim3(DM / BN, (BATCH * S_LEN) / BM, 3), 256, 0, stream>>>(
      hs, Wt, bq, bk, bv, Qb, Kf, Vf);
  attn_fused<<<dim3((S_LEN / 32) * NH * BATCH), 256, 0, stream>>>(
      Qb, (const bf16x8*)Kf, (const bf16x8*)Vf, mask, ctx, Pout);
}